// Round 8
// baseline (434.531 us; speedup 1.0000x reference)
//
#include <hip/hip_runtime.h>
#include <hip/hip_bf16.h>
#include <math.h>

#define B_  4
#define S_  2048
#define D_  1024
#define NH_ 16
#define HD_ 64

typedef __attribute__((ext_vector_type(8))) short bf16x8;
typedef __attribute__((ext_vector_type(4))) float f32x4;
typedef __attribute__((ext_vector_type(4))) uint  u32x4;

#define VMCNT(n)  asm volatile("s_waitcnt vmcnt(" #n ")" ::: "memory")
#define LGKMCNT0  asm volatile("s_waitcnt lgkmcnt(0)" ::: "memory")
#define SCHEDB()  __builtin_amdgcn_sched_barrier(0)
#define BARRIER() __builtin_amdgcn_s_barrier()

__device__ inline ushort f2bf(float f) {
    uint u = __builtin_bit_cast(uint, f);
    uint r = (u + 0x7fffu + ((u >> 16) & 1u)) >> 16;   // RTNE
    return (ushort)r;
}

__device__ inline uint cvt_pk_bf16(float lo, float hi) {
    uint r;
    asm volatile("v_cvt_pk_bf16_f32 %0, %1, %2" : "=v"(r) : "v"(lo), "v"(hi));
    return r;
}

// ---------------------------------------------------------------------------
// casts
// ---------------------------------------------------------------------------
__global__ __launch_bounds__(256) void cast_x(const float* __restrict__ in,
                                              ushort* __restrict__ out, int n) {
    int i = (blockIdx.x * 256 + threadIdx.x) * 4;
    if (i < n) {
        float4 f = *reinterpret_cast<const float4*>(&in[i]);
        ushort4 o = {f2bf(f.x), f2bf(f.y), f2bf(f.z), f2bf(f.w)};
        *reinterpret_cast<ushort4*>(&out[i]) = o;
    }
}

__global__ __launch_bounds__(256) void cast_w4(const float* __restrict__ w0,
                                               const float* __restrict__ w1,
                                               const float* __restrict__ w2,
                                               const float* __restrict__ w3,
                                               ushort* __restrict__ o, int n) {
    const float* src = (blockIdx.y == 0) ? w0 : (blockIdx.y == 1) ? w1
                     : (blockIdx.y == 2) ? w2 : w3;
    ushort* dst = o + (size_t)blockIdx.y * n;
    int i = (blockIdx.x * 256 + threadIdx.x) * 4;
    if (i < n) {
        float4 f = *reinterpret_cast<const float4*>(&src[i]);
        ushort4 v = {f2bf(f.x), f2bf(f.y), f2bf(f.z), f2bf(f.w)};
        *reinterpret_cast<ushort4*>(&dst[i]) = v;
    }
}

// ---------------------------------------------------------------------------
// bf16 MFMA GEMM, 128x128 tile, BK=32, 4 waves, m97 staging + XCD swizzle.
// MODE 0: fused QKV (W rows = 3072), bf16 out, tensor 0 scaled by 0.125*log2e.
// MODE 1: f32 out (out-projection).
// ---------------------------------------------------------------------------
template <int MODE>
__global__ __launch_bounds__(256) void gemm128(const ushort* __restrict__ A,
                                               const ushort* __restrict__ W,
                                               void* __restrict__ Cv,
                                               int M, int Nw, int K) {
    __shared__ ushort As[128 * 32];
    __shared__ ushort Ws[128 * 32];
    const int tid = threadIdx.x;

    const int gx = gridDim.x;
    const int nwg = gx * gridDim.y;
    const int f = blockIdx.y * gx + blockIdx.x;
    const int cpx = nwg >> 3;
    const int tileid = (f & 7) * cpx + (f >> 3);
    const int m0 = (tileid / gx) * 128;
    const int n0 = (tileid % gx) * 128;

    const int lane = tid & 63;
    const int w = tid >> 6;
    const int wr = (w >> 1) * 64;
    const int wc = (w & 1) * 64;
    const int fr = lane & 15;
    const int fq = lane >> 4;

    f32x4 acc[4][4] = {};

    for (int k0 = 0; k0 < K; k0 += 32) {
#pragma unroll
        for (int it = 0; it < 2; ++it) {
            int c = tid + it * 256;
            int row = c >> 2;
            int col = (c & 3) * 8;
            const ushort* ga = &A[(size_t)(m0 + row) * K + k0 + col];
            const ushort* gw = &W[(size_t)(n0 + row) * K + k0 + col];
            __builtin_amdgcn_global_load_lds(
                (const __attribute__((address_space(1))) uint32_t*)((const void*)ga),
                (__attribute__((address_space(3))) uint32_t*)((void*)&As[c * 8]), 16, 0, 0);
            __builtin_amdgcn_global_load_lds(
                (const __attribute__((address_space(1))) uint32_t*)((const void*)gw),
                (__attribute__((address_space(3))) uint32_t*)((void*)&Ws[c * 8]), 16, 0, 0);
        }
        __syncthreads();

        bf16x8 af[4], bfv[4];
#pragma unroll
        for (int m = 0; m < 4; ++m)
            af[m] = *reinterpret_cast<const bf16x8*>(&As[(wr + m * 16 + fr) * 32 + fq * 8]);
#pragma unroll
        for (int n = 0; n < 4; ++n)
            bfv[n] = *reinterpret_cast<const bf16x8*>(&Ws[(wc + n * 16 + fr) * 32 + fq * 8]);
#pragma unroll
        for (int m = 0; m < 4; ++m)
#pragma unroll
            for (int n = 0; n < 4; ++n)
                acc[m][n] = __builtin_amdgcn_mfma_f32_16x16x32_bf16(af[m], bfv[n], acc[m][n], 0, 0, 0);
        __syncthreads();
    }

    if (MODE == 0) {
        const int tensor = n0 >> 10;
        ushort* C = (ushort*)Cv + (size_t)tensor * ((size_t)M * 1024);
        const float sc = (tensor == 0) ? 0.18033688011112042f : 1.0f;  // 0.125*log2e
        const int nb = n0 & 1023;
#pragma unroll
        for (int m = 0; m < 4; ++m)
#pragma unroll
            for (int n = 0; n < 4; ++n) {
                int col = nb + wc + n * 16 + fr;
                int rowb = m0 + wr + m * 16 + fq * 4;
#pragma unroll
                for (int r = 0; r < 4; ++r)
                    C[(size_t)(rowb + r) * 1024 + col] = f2bf(acc[m][n][r] * sc);
            }
    } else {
        float* C = (float*)Cv;
#pragma unroll
        for (int m = 0; m < 4; ++m)
#pragma unroll
            for (int n = 0; n < 4; ++n) {
                int col = n0 + wc + n * 16 + fr;
                int rowb = m0 + wr + m * 16 + fq * 4;
#pragma unroll
                for (int r = 0; r < 4; ++r)
                    C[(size_t)(rowb + r) * Nw + col] = acc[m][n][r];
            }
    }
}

// ---------------------------------------------------------------------------
// MFMA flash attention v7: T15 cross-tile pipeline. QK^T(t+1) is issued
// BEFORE softmax+PV(t), so softmax reads scores whose MFMAs retired a full
// tile ago (MFMA+shfl latency hidden under the matrix pipe / other work).
// Two named score sets (scA/scB, loop unrolled x2), 3 K-buffers + 2 V-buffers
// (40KB LDS -> still 4 blocks/CU). Counted vmcnt across raw s_barrier.
// XCD bh-grouping keeps K/V in one XCD's L2 (FETCH ~31MB, ideal).
// ---------------------------------------------------------------------------
__global__ __launch_bounds__(256, 4) void attn_mfma(const ushort* __restrict__ Qg,
                                                    const ushort* __restrict__ Kg,
                                                    const ushort* __restrict__ Vg,
                                                    ushort* __restrict__ Yg) {
    __shared__ ushort SH[5 * 4096];   // K bufs 0,1,2 ; V bufs 3,4 (8KB each)

    const int tid = threadIdx.x;
    const int lane = tid & 63;
    const int w = tid >> 6;
    const int fr = lane & 15;
    const int fq = lane >> 4;

    // XCD grouping: all 16 q-tiles of a bh land on one XCD
    const int lin = blockIdx.x;
    const int qt = (lin >> 3) & 15;
    const int bh = (lin & 7) * 8 + (lin >> 7);
    const int b = bh >> 4;
    const int h = bh & 15;
    const size_t hbase = (size_t)b * (S_ * D_) + (size_t)h * HD_;
    const int NT = S_ / 64;           // 32

    // Q fragments from global (one-time)
    bf16x8 qf[2][2];
#pragma unroll
    for (int m = 0; m < 2; ++m)
#pragma unroll
        for (int kk = 0; kk < 2; ++kk)
            qf[m][kk] = *reinterpret_cast<const bf16x8*>(
                &Qg[hbase + (size_t)(qt * 128 + w * 32 + m * 16 + fr) * D_ + kk * 32 + fq * 8]);

    // swizzled LDS read offsets (ushort units, within one 4096-elem buffer)
    uint rdoff[2][4];
#pragma unroll
    for (int kk = 0; kk < 2; ++kk)
#pragma unroll
        for (int n = 0; n < 4; ++n)
            rdoff[kk][n] = (uint)((n * 16 + fr) * 64 + 8 * (((kk << 2) + fq) ^ (fr & 7)));
    uint vwoff[2];
#pragma unroll
    for (int t = 0; t < 2; ++t)
        vwoff[t] = (uint)(lane * 64 + 8 * (((w << 1) + t) ^ (lane & 7)));

    // K DMA per-thread constants
    const int c0i = tid, c1i = tid + 256;
    const int krow0 = c0i >> 3, kslot0 = (c0i & 7) ^ (krow0 & 7);
    const int krow1 = c1i >> 3, kslot1 = (c1i & 7) ^ (krow1 & 7);

    float mr[2], lrun[2];
    f32x4 oy[2][4] = {};
    mr[0] = mr[1] = -1e30f;
    lrun[0] = lrun[1] = 0.f;

    uint vpk[8];   // next V tile, packed pairs

    auto STAGEK = [&](int kt, int kbase) {
        const ushort* g0 = &Kg[hbase + (size_t)(kt * 64 + krow0) * D_ + kslot0 * 8];
        const ushort* g1 = &Kg[hbase + (size_t)(kt * 64 + krow1) * D_ + kslot1 * 8];
        __builtin_amdgcn_global_load_lds(
            (const __attribute__((address_space(1))) uint32_t*)((const void*)g0),
            (__attribute__((address_space(3))) uint32_t*)((void*)&SH[kbase + c0i * 8]), 16, 0, 0);
        __builtin_amdgcn_global_load_lds(
            (const __attribute__((address_space(1))) uint32_t*)((const void*)g1),
            (__attribute__((address_space(3))) uint32_t*)((void*)&SH[kbase + c1i * 8]), 16, 0, 0);
    };
    auto VLOAD = [&](int kt) {
        const ushort* vp = &Vg[hbase + (size_t)(kt * 64) * D_ + lane];
#pragma unroll
        for (int jj = 0; jj < 8; ++jj) {
            int c = w * 16 + jj * 2;
            int key = (c & 32) + ((c >> 3) & 3) * 4 + (c & 3) + ((c >> 2) & 1) * 16;
            uint lo = vp[(size_t)key * D_];
            uint hi = vp[(size_t)(key + 1) * D_];
            vpk[jj] = lo | (hi << 16);
        }
    };
    auto VWRITE = [&](int vbase) {
#pragma unroll
        for (int t = 0; t < 2; ++t) {
            u32x4 a = {vpk[t * 4 + 0], vpk[t * 4 + 1], vpk[t * 4 + 2], vpk[t * 4 + 3]};
            *reinterpret_cast<bf16x8*>(&SH[vbase + vwoff[t]]) =
                __builtin_bit_cast(bf16x8, a);
        }
    };
    auto QKT = [&](f32x4 (&sc)[2][4], int kbase) {
#pragma unroll
        for (int m = 0; m < 2; ++m)
#pragma unroll
            for (int n = 0; n < 4; ++n) sc[m][n] = f32x4{0.f, 0.f, 0.f, 0.f};
        __builtin_amdgcn_s_setprio(1);
#pragma unroll
        for (int kk = 0; kk < 2; ++kk)
#pragma unroll
            for (int n = 0; n < 4; ++n) {
                bf16x8 kf = *reinterpret_cast<const bf16x8*>(&SH[kbase + rdoff[kk][n]]);
                sc[0][n] = __builtin_amdgcn_mfma_f32_16x16x32_bf16(kf, qf[0][kk], sc[0][n], 0, 0, 0);
                sc[1][n] = __builtin_amdgcn_mfma_f32_16x16x32_bf16(kf, qf[1][kk], sc[1][n], 0, 0, 0);
            }
        __builtin_amdgcn_s_setprio(0);
    };
    auto SMPV = [&](f32x4 (&sc)[2][4], int vbase) {
        uint pk[2][4][2];
#pragma unroll
        for (int m = 0; m < 2; ++m) {
            float q0 = fmaxf(fmaxf(sc[m][0][0], sc[m][0][1]), fmaxf(sc[m][0][2], sc[m][0][3]));
            float q1 = fmaxf(fmaxf(sc[m][1][0], sc[m][1][1]), fmaxf(sc[m][1][2], sc[m][1][3]));
            float q2 = fmaxf(fmaxf(sc[m][2][0], sc[m][2][1]), fmaxf(sc[m][2][2], sc[m][2][3]));
            float q3 = fmaxf(fmaxf(sc[m][3][0], sc[m][3][1]), fmaxf(sc[m][3][2], sc[m][3][3]));
            float mx = fmaxf(fmaxf(q0, q1), fmaxf(q2, q3));
            mx = fmaxf(mx, __shfl_xor(mx, 16));
            mx = fmaxf(mx, __shfl_xor(mx, 32));
            if (!__all(mx - mr[m] <= 8.f)) {
                float mnew = fmaxf(mr[m], mx);
                float corr = exp2f(mr[m] - mnew);
                mr[m] = mnew;
                lrun[m] *= corr;
#pragma unroll
                for (int r = 0; r < 4; ++r) {
                    float cb = __shfl(corr, fq * 4 + r);
#pragma unroll
                    for (int n = 0; n < 4; ++n) oy[m][n][r] *= cb;
                }
            }
#pragma unroll
            for (int n = 0; n < 4; ++n)
#pragma unroll
                for (int r = 0; r < 4; ++r)
                    sc[m][n][r] = exp2f(sc[m][n][r] - mr[m]);
            float s0 = (sc[m][0][0] + sc[m][0][1]) + (sc[m][0][2] + sc[m][0][3]);
            float s1 = (sc[m][1][0] + sc[m][1][1]) + (sc[m][1][2] + sc[m][1][3]);
            float s2 = (sc[m][2][0] + sc[m][2][1]) + (sc[m][2][2] + sc[m][2][3]);
            float s3 = (sc[m][3][0] + sc[m][3][1]) + (sc[m][3][2] + sc[m][3][3]);
            float rs = (s0 + s1) + (s2 + s3);
            rs += __shfl_xor(rs, 16);
            rs += __shfl_xor(rs, 32);
            lrun[m] += rs;
#pragma unroll
            for (int n = 0; n < 4; ++n) {
                pk[m][n][0] = cvt_pk_bf16(sc[m][n][0], sc[m][n][1]);
                pk[m][n][1] = cvt_pk_bf16(sc[m][n][2], sc[m][n][3]);
            }
        }
        __builtin_amdgcn_s_setprio(1);
#pragma unroll
        for (int kk = 0; kk < 2; ++kk) {
            u32x4 a0 = {pk[0][2 * kk][0], pk[0][2 * kk][1], pk[0][2 * kk + 1][0], pk[0][2 * kk + 1][1]};
            u32x4 a1 = {pk[1][2 * kk][0], pk[1][2 * kk][1], pk[1][2 * kk + 1][0], pk[1][2 * kk + 1][1]};
            bf16x8 pf0 = __builtin_bit_cast(bf16x8, a0);
            bf16x8 pf1 = __builtin_bit_cast(bf16x8, a1);
#pragma unroll
            for (int n = 0; n < 4; ++n) {
                bf16x8 vf = *reinterpret_cast<const bf16x8*>(&SH[vbase + rdoff[kk][n]]);
                oy[0][n] = __builtin_amdgcn_mfma_f32_16x16x32_bf16(pf0, vf, oy[0][n], 0, 0, 0);
                oy[1][n] = __builtin_amdgcn_mfma_f32_16x16x32_bf16(pf1, vf, oy[1][n], 0, 0, 0);
            }
        }
        __builtin_amdgcn_s_setprio(0);
    };

    f32x4 scA[2][4], scB[2][4];
    const int V0 = 3 * 4096, V1 = 4 * 4096;

    // ---- prologue ----
    VLOAD(0);
    VWRITE(V0);                       // V(0)
    STAGEK(0, 0 * 4096); SCHEDB();
    STAGEK(1, 1 * 4096); SCHEDB();
    VLOAD(1);
    VMCNT(16);                        // K0,K1 DMAs retired; V(1) x16 in flight
    LGKMCNT0;
    BARRIER(); SCHEDB();
    QKT(scA, 0 * 4096);               // scores(0)

    int ka = 0 * 4096, kb = 1 * 4096, kc = 2 * 4096;

    // ---- main loop: tiles t (even, scA) and t+1 (odd, scB), t = 0..NT-4 ----
    for (int t = 0; t < NT - 2; t += 2) {
        // half A: tile t
        VWRITE((t + 1) & 1 ? V1 : V0);            // V(t+1)
        STAGEK(t + 2, kc); SCHEDB();
        QKT(scB, kb);                             // scores(t+1)
        VLOAD(t + 2);
        SMPV(scA, (t & 1) ? V1 : V0);             // softmax+PV(t)
        VMCNT(16); LGKMCNT0; BARRIER(); SCHEDB();
        { int tmp = ka; ka = kb; kb = kc; kc = tmp; }
        // half B: tile t+1
        VWRITE((t + 2) & 1 ? V1 : V0);            // V(t+2)
        STAGEK(t + 3, kc); SCHEDB();
        QKT(scA, kb);                             // scores(t+2)
        VLOAD(t + 3);
        SMPV(scB, ((t + 1) & 1) ? V1 : V0);       // softmax+PV(t+1)
        VMCNT(16); LGKMCNT0; BARRIER(); SCHEDB();
        { int tmp = ka; ka = kb; kb = kc; kc = tmp; }
    }
    // ---- peel t = NT-2 ----
    VWRITE((NT - 1) & 1 ? V1 : V0);               // V(NT-1)
    QKT(scB, kb);                                 // scores(NT-1)
    SMPV(scA, ((NT - 2) & 1) ? V1 : V0);
    VMCNT(0); LGKMCNT0; BARRIER(); SCHEDB();
    // ---- peel t = NT-1 ----
    SMPV(scB, ((NT - 1) & 1) ? V1 : V0);

    // epilogue
#pragma unroll
    for (int m = 0; m < 2; ++m) {
#pragma unroll
        for (int r = 0; r < 4; ++r) {
            float lb = __shfl(lrun[m], fq * 4 + r);
            float inv = 1.0f / lb;
            int row = qt * 128 + w * 32 + m * 16 + fq * 4 + r;
#pragma unroll
            for (int n = 0; n < 4; ++n)
                Yg[hbase + (size_t)row * D_ + n * 16 + fr] = f2bf(oy[m][n][r] * inv);
        }
    }
}

// ---------------------------------------------------------------------------
extern "C" void kernel_launch(void* const* d_in, const int* in_sizes, int n_in,
                              void* d_out, int out_size, void* d_ws, size_t ws_size,
                              hipStream_t stream) {
    const float* x  = (const float*)d_in[0];
    const float* Wq = (const float*)d_in[1];
    const float* Wk = (const float*)d_in[2];
    const float* Wv = (const float*)d_in[3];
    const float* Wo = (const float*)d_in[4];
    float* out = (float*)d_out;

    const size_t nx = (size_t)B_ * S_ * D_;
    const size_t nw = (size_t)D_ * D_;

    ushort* xb = (ushort*)d_ws;
    ushort* wb = xb + nx;          // Wq,Wk,Wv,Wo contiguous -> [4096][1024]
    ushort* qb = wb + 4 * nw;      // q,k,v contiguous
    ushort* kb = qb + nx;
    ushort* vb = kb + nx;
    ushort* yb = vb + nx;

    dim3 blk(256);
    hipLaunchKernelGGL(cast_x, dim3((nx / 4 + 255) / 256), blk, 0, stream, x, xb, (int)nx);
    hipLaunchKernelGGL(cast_w4, dim3((nw / 4 + 255) / 256, 4), blk, 0, stream,
                       Wq, Wk, Wv, Wo, wb, (int)nw);

    const int M = B_ * S_;
    dim3 gqkv(3072 / 128, M / 128);           // 1536 blocks, %8==0
    hipLaunchKernelGGL((gemm128<0>), gqkv, blk, 0, stream, xb, wb, qb, M, 3072, D_);

    dim3 gattn(1024);                         // linear; kernel does XCD grouping
    hipLaunchKernelGGL(attn_mfma, gattn, blk, 0, stream, qb, kb, vb, yb);

    dim3 gproj(D_ / 128, M / 128);            // 512 blocks
    hipLaunchKernelGGL((gemm128<1>), gproj, blk, 0, stream, yb, wb + 3 * nw, out, M, D_, D_);
}

// Round 9
// 249.560 us; speedup vs baseline: 1.7412x; 1.7412x over previous
//
#include <hip/hip_runtime.h>
#include <hip/hip_bf16.h>
#include <math.h>

#define B_  4
#define S_  2048
#define D_  1024
#define NH_ 16
#define HD_ 64

typedef __attribute__((ext_vector_type(8))) short bf16x8;
typedef __attribute__((ext_vector_type(4))) float f32x4;
typedef __attribute__((ext_vector_type(4))) uint  u32x4;

#define VMCNT(n)  asm volatile("s_waitcnt vmcnt(" #n ")" ::: "memory")
#define LGKMCNT0  asm volatile("s_waitcnt lgkmcnt(0)" ::: "memory")
#define SCHEDB()  __builtin_amdgcn_sched_barrier(0)
#define BARRIER() __builtin_amdgcn_s_barrier()

__device__ inline ushort f2bf(float f) {
    uint u = __builtin_bit_cast(uint, f);
    uint r = (u + 0x7fffu + ((u >> 16) & 1u)) >> 16;   // RTNE
    return (ushort)r;
}

__device__ inline uint cvt_pk_bf16(float lo, float hi) {
    uint r;
    asm volatile("v_cvt_pk_bf16_f32 %0, %1, %2" : "=v"(r) : "v"(lo), "v"(hi));
    return r;
}

// ---------------------------------------------------------------------------
// casts
// ---------------------------------------------------------------------------
__global__ __launch_bounds__(256) void cast_x(const float* __restrict__ in,
                                              ushort* __restrict__ out, int n) {
    int i = (blockIdx.x * 256 + threadIdx.x) * 4;
    if (i < n) {
        float4 f = *reinterpret_cast<const float4*>(&in[i]);
        ushort4 o = {f2bf(f.x), f2bf(f.y), f2bf(f.z), f2bf(f.w)};
        *reinterpret_cast<ushort4*>(&out[i]) = o;
    }
}

__global__ __launch_bounds__(256) void cast_w4(const float* __restrict__ w0,
                                               const float* __restrict__ w1,
                                               const float* __restrict__ w2,
                                               const float* __restrict__ w3,
                                               ushort* __restrict__ o, int n) {
    const float* src = (blockIdx.y == 0) ? w0 : (blockIdx.y == 1) ? w1
                     : (blockIdx.y == 2) ? w2 : w3;
    ushort* dst = o + (size_t)blockIdx.y * n;
    int i = (blockIdx.x * 256 + threadIdx.x) * 4;
    if (i < n) {
        float4 f = *reinterpret_cast<const float4*>(&src[i]);
        ushort4 v = {f2bf(f.x), f2bf(f.y), f2bf(f.z), f2bf(f.w)};
        *reinterpret_cast<ushort4*>(&dst[i]) = v;
    }
}

// ---------------------------------------------------------------------------
// bf16 MFMA GEMM, 128x128 tile, BK=32, 4 waves, m97 staging + XCD swizzle.
// MODE 0: fused QKV (W rows = 3072), bf16 out, tensor 0 scaled by 0.125*log2e.
// MODE 1: f32 out (out-projection).
// ---------------------------------------------------------------------------
template <int MODE>
__global__ __launch_bounds__(256) void gemm128(const ushort* __restrict__ A,
                                               const ushort* __restrict__ W,
                                               void* __restrict__ Cv,
                                               int M, int Nw, int K) {
    __shared__ ushort As[128 * 32];
    __shared__ ushort Ws[128 * 32];
    const int tid = threadIdx.x;

    const int gx = gridDim.x;
    const int nwg = gx * gridDim.y;
    const int f = blockIdx.y * gx + blockIdx.x;
    const int cpx = nwg >> 3;
    const int tileid = (f & 7) * cpx + (f >> 3);
    const int m0 = (tileid / gx) * 128;
    const int n0 = (tileid % gx) * 128;

    const int lane = tid & 63;
    const int w = tid >> 6;
    const int wr = (w >> 1) * 64;
    const int wc = (w & 1) * 64;
    const int fr = lane & 15;
    const int fq = lane >> 4;

    f32x4 acc[4][4] = {};

    for (int k0 = 0; k0 < K; k0 += 32) {
#pragma unroll
        for (int it = 0; it < 2; ++it) {
            int c = tid + it * 256;
            int row = c >> 2;
            int col = (c & 3) * 8;
            const ushort* ga = &A[(size_t)(m0 + row) * K + k0 + col];
            const ushort* gw = &W[(size_t)(n0 + row) * K + k0 + col];
            __builtin_amdgcn_global_load_lds(
                (const __attribute__((address_space(1))) uint32_t*)((const void*)ga),
                (__attribute__((address_space(3))) uint32_t*)((void*)&As[c * 8]), 16, 0, 0);
            __builtin_amdgcn_global_load_lds(
                (const __attribute__((address_space(1))) uint32_t*)((const void*)gw),
                (__attribute__((address_space(3))) uint32_t*)((void*)&Ws[c * 8]), 16, 0, 0);
        }
        __syncthreads();

        bf16x8 af[4], bfv[4];
#pragma unroll
        for (int m = 0; m < 4; ++m)
            af[m] = *reinterpret_cast<const bf16x8*>(&As[(wr + m * 16 + fr) * 32 + fq * 8]);
#pragma unroll
        for (int n = 0; n < 4; ++n)
            bfv[n] = *reinterpret_cast<const bf16x8*>(&Ws[(wc + n * 16 + fr) * 32 + fq * 8]);
#pragma unroll
        for (int m = 0; m < 4; ++m)
#pragma unroll
            for (int n = 0; n < 4; ++n)
                acc[m][n] = __builtin_amdgcn_mfma_f32_16x16x32_bf16(af[m], bfv[n], acc[m][n], 0, 0, 0);
        __syncthreads();
    }

    if (MODE == 0) {
        const int tensor = n0 >> 10;
        ushort* C = (ushort*)Cv + (size_t)tensor * ((size_t)M * 1024);
        const float sc = (tensor == 0) ? 0.18033688011112042f : 1.0f;  // 0.125*log2e
        const int nb = n0 & 1023;
#pragma unroll
        for (int m = 0; m < 4; ++m)
#pragma unroll
            for (int n = 0; n < 4; ++n) {
                int col = nb + wc + n * 16 + fr;
                int rowb = m0 + wr + m * 16 + fq * 4;
#pragma unroll
                for (int r = 0; r < 4; ++r)
                    C[(size_t)(rowb + r) * 1024 + col] = f2bf(acc[m][n][r] * sc);
            }
    } else {
        float* C = (float*)Cv;
#pragma unroll
        for (int m = 0; m < 4; ++m)
#pragma unroll
            for (int n = 0; n < 4; ++n) {
                int col = n0 + wc + n * 16 + fr;
                int rowb = m0 + wr + m * 16 + fq * 4;
#pragma unroll
                for (int r = 0; r < 4; ++r)
                    C[(size_t)(rowb + r) * Nw + col] = acc[m][n][r];
            }
    }
}

// ---------------------------------------------------------------------------
// MFMA flash attention v8: R6 structure (known-good 2-buffer, single sc,
// counted vmcnt across raw s_barrier, XCD bh-grouping) with QBLK = 64:
// grid 2048 blocks, 4 waves x 16 q-rows. LDS stays 32KB -> 5 blocks/CU
// (occupancy probe: waves/SIMD 4 -> 5, halved per-wave register state,
// inter-block desync). Everything else identical to the 143.7us R6 kernel.
// ---------------------------------------------------------------------------
__global__ __launch_bounds__(256, 4) void attn_mfma(const ushort* __restrict__ Qg,
                                                    const ushort* __restrict__ Kg,
                                                    const ushort* __restrict__ Vg,
                                                    ushort* __restrict__ Yg) {
    __shared__ ushort SH[2 * 8192];   // buf b: K at b*8192, V at b*8192+4096

    const int tid = threadIdx.x;
    const int lane = tid & 63;
    const int w = tid >> 6;
    const int fr = lane & 15;
    const int fq = lane >> 4;

    // XCD grouping: all 32 q-tiles of a bh land on one XCD
    const int lin = blockIdx.x;           // 0..2047
    const int qt = (lin >> 3) & 31;       // 32 q-tiles of 64 rows
    const int bh = (lin & 7) * 8 + (lin >> 8);
    const int b = bh >> 4;
    const int h = bh & 15;
    const size_t hbase = (size_t)b * (S_ * D_) + (size_t)h * HD_;
    const int NT = S_ / 64;               // 32

    // Q fragments from global (one-time): wave owns rows qt*64 + w*16 + fr
    bf16x8 qf[2];
#pragma unroll
    for (int kk = 0; kk < 2; ++kk)
        qf[kk] = *reinterpret_cast<const bf16x8*>(
            &Qg[hbase + (size_t)(qt * 64 + w * 16 + fr) * D_ + kk * 32 + fq * 8]);

    // swizzled LDS read offsets (ushort units)
    uint rdoff[2][4];
#pragma unroll
    for (int kk = 0; kk < 2; ++kk)
#pragma unroll
        for (int n = 0; n < 4; ++n)
            rdoff[kk][n] = (uint)((n * 16 + fr) * 64 + 8 * (((kk << 2) + fq) ^ (fr & 7)));
    uint vwoff[2];
#pragma unroll
    for (int t = 0; t < 2; ++t)
        vwoff[t] = (uint)(lane * 64 + 8 * (((w << 1) + t) ^ (lane & 7)));

    // K DMA per-thread constants
    const int c0i = tid, c1i = tid + 256;
    const int krow0 = c0i >> 3, kslot0 = (c0i & 7) ^ (krow0 & 7);
    const int krow1 = c1i >> 3, kslot1 = (c1i & 7) ^ (krow1 & 7);

    float mr = -1e30f, lrun = 0.f;
    f32x4 oy[4] = {};

    uint vpk[8];   // next V tile, packed pairs

    auto STAGEK = [&](int kt, int bb) {
        const ushort* g0 = &Kg[hbase + (size_t)(kt * 64 + krow0) * D_ + kslot0 * 8];
        const ushort* g1 = &Kg[hbase + (size_t)(kt * 64 + krow1) * D_ + kslot1 * 8];
        __builtin_amdgcn_global_load_lds(
            (const __attribute__((address_space(1))) uint32_t*)((const void*)g0),
            (__attribute__((address_space(3))) uint32_t*)((void*)&SH[bb + c0i * 8]), 16, 0, 0);
        __builtin_amdgcn_global_load_lds(
            (const __attribute__((address_space(1))) uint32_t*)((const void*)g1),
            (__attribute__((address_space(3))) uint32_t*)((void*)&SH[bb + c1i * 8]), 16, 0, 0);
    };
    auto VLOAD = [&](int kt) {
        const ushort* vp = &Vg[hbase + (size_t)(kt * 64) * D_ + lane];
#pragma unroll
        for (int jj = 0; jj < 8; ++jj) {
            int c = w * 16 + jj * 2;
            int key = (c & 32) + ((c >> 3) & 3) * 4 + (c & 3) + ((c >> 2) & 1) * 16;
            uint lo = vp[(size_t)key * D_];
            uint hi = vp[(size_t)(key + 1) * D_];
            vpk[jj] = lo | (hi << 16);
        }
    };
    auto VWRITE = [&](int bb) {
#pragma unroll
        for (int t = 0; t < 2; ++t) {
            u32x4 a = {vpk[t * 4 + 0], vpk[t * 4 + 1], vpk[t * 4 + 2], vpk[t * 4 + 3]};
            *reinterpret_cast<bf16x8*>(&SH[bb + 4096 + vwoff[t]]) =
                __builtin_bit_cast(bf16x8, a);
        }
    };
    auto QKT = [&](f32x4 (&sc)[4], int bb) {
#pragma unroll
        for (int n = 0; n < 4; ++n) sc[n] = f32x4{0.f, 0.f, 0.f, 0.f};
        __builtin_amdgcn_s_setprio(1);
#pragma unroll
        for (int kk = 0; kk < 2; ++kk)
#pragma unroll
            for (int n = 0; n < 4; ++n) {
                bf16x8 kf = *reinterpret_cast<const bf16x8*>(&SH[bb + rdoff[kk][n]]);
                sc[n] = __builtin_amdgcn_mfma_f32_16x16x32_bf16(kf, qf[kk], sc[n], 0, 0, 0);
            }
        __builtin_amdgcn_s_setprio(0);
    };
    auto SMPV = [&](f32x4 (&sc)[4], int bb) {
        uint pk[4][2];
        float q0 = fmaxf(fmaxf(sc[0][0], sc[0][1]), fmaxf(sc[0][2], sc[0][3]));
        float q1 = fmaxf(fmaxf(sc[1][0], sc[1][1]), fmaxf(sc[1][2], sc[1][3]));
        float q2 = fmaxf(fmaxf(sc[2][0], sc[2][1]), fmaxf(sc[2][2], sc[2][3]));
        float q3 = fmaxf(fmaxf(sc[3][0], sc[3][1]), fmaxf(sc[3][2], sc[3][3]));
        float mx = fmaxf(fmaxf(q0, q1), fmaxf(q2, q3));
        mx = fmaxf(mx, __shfl_xor(mx, 16));
        mx = fmaxf(mx, __shfl_xor(mx, 32));
        if (!__all(mx - mr <= 8.f)) {
            float mnew = fmaxf(mr, mx);
            float corr = exp2f(mr - mnew);
            mr = mnew;
            lrun *= corr;
#pragma unroll
            for (int r = 0; r < 4; ++r) {
                float cb = __shfl(corr, fq * 4 + r);
#pragma unroll
                for (int n = 0; n < 4; ++n) oy[n][r] *= cb;
            }
        }
#pragma unroll
        for (int n = 0; n < 4; ++n)
#pragma unroll
            for (int r = 0; r < 4; ++r)
                sc[n][r] = exp2f(sc[n][r] - mr);
        float s0 = (sc[0][0] + sc[0][1]) + (sc[0][2] + sc[0][3]);
        float s1 = (sc[1][0] + sc[1][1]) + (sc[1][2] + sc[1][3]);
        float s2 = (sc[2][0] + sc[2][1]) + (sc[2][2] + sc[2][3]);
        float s3 = (sc[3][0] + sc[3][1]) + (sc[3][2] + sc[3][3]);
        float rs = (s0 + s1) + (s2 + s3);
        rs += __shfl_xor(rs, 16);
        rs += __shfl_xor(rs, 32);
        lrun += rs;
#pragma unroll
        for (int n = 0; n < 4; ++n) {
            pk[n][0] = cvt_pk_bf16(sc[n][0], sc[n][1]);
            pk[n][1] = cvt_pk_bf16(sc[n][2], sc[n][3]);
        }
        __builtin_amdgcn_s_setprio(1);
#pragma unroll
        for (int kk = 0; kk < 2; ++kk) {
            u32x4 a0 = {pk[2 * kk][0], pk[2 * kk][1], pk[2 * kk + 1][0], pk[2 * kk + 1][1]};
            bf16x8 pf0 = __builtin_bit_cast(bf16x8, a0);
#pragma unroll
            for (int n = 0; n < 4; ++n) {
                bf16x8 vf = *reinterpret_cast<const bf16x8*>(&SH[bb + 4096 + rdoff[kk][n]]);
                oy[n] = __builtin_amdgcn_mfma_f32_16x16x32_bf16(pf0, vf, oy[n], 0, 0, 0);
            }
        }
        __builtin_amdgcn_s_setprio(0);
    };

    // ---- prologue ----
    VLOAD(0);
    VWRITE(0);
    STAGEK(0, 0);
    SCHEDB();          // pin the 2 DMAs before the V(1) loads (exact FIFO count)
    VLOAD(1);
    VMCNT(16);         // K0 DMA retired; V(1) x16 in flight
    LGKMCNT0;          // V0 ds_write visible
    BARRIER();
    SCHEDB();

    f32x4 sc[4];
    // ---- main loop ----
    for (int t = 0; t < NT - 2; ++t) {
        const int A = (t & 1) * 8192, Bb = 8192 - A;
        STAGEK(t + 1, Bb);
        SCHEDB();
        QKT(sc, A);
        VWRITE(Bb);
        VLOAD(t + 2);
        SMPV(sc, A);
        VMCNT(16);
        LGKMCNT0;
        BARRIER();
        SCHEDB();
    }
    // ---- t = NT-2 ----
    {
        const int A = ((NT - 2) & 1) * 8192, Bb = 8192 - A;
        STAGEK(NT - 1, Bb);
        SCHEDB();
        QKT(sc, A);
        VWRITE(Bb);
        SMPV(sc, A);
        VMCNT(0);
        LGKMCNT0;
        BARRIER();
        SCHEDB();
    }
    // ---- t = NT-1 ----
    {
        const int A = ((NT - 1) & 1) * 8192;
        QKT(sc, A);
        SMPV(sc, A);
    }

    // epilogue
#pragma unroll
    for (int r = 0; r < 4; ++r) {
        float lb = __shfl(lrun, fq * 4 + r);
        float inv = 1.0f / lb;
        int row = qt * 64 + w * 16 + fq * 4 + r;
#pragma unroll
        for (int n = 0; n < 4; ++n)
            Yg[hbase + (size_t)row * D_ + n * 16 + fr] = f2bf(oy[n][r] * inv);
    }
}

// ---------------------------------------------------------------------------
extern "C" void kernel_launch(void* const* d_in, const int* in_sizes, int n_in,
                              void* d_out, int out_size, void* d_ws, size_t ws_size,
                              hipStream_t stream) {
    const float* x  = (const float*)d_in[0];
    const float* Wq = (const float*)d_in[1];
    const float* Wk = (const float*)d_in[2];
    const float* Wv = (const float*)d_in[3];
    const float* Wo = (const float*)d_in[4];
    float* out = (float*)d_out;

    const size_t nx = (size_t)B_ * S_ * D_;
    const size_t nw = (size_t)D_ * D_;

    ushort* xb = (ushort*)d_ws;
    ushort* wb = xb + nx;          // Wq,Wk,Wv,Wo contiguous -> [4096][1024]
    ushort* qb = wb + 4 * nw;      // q,k,v contiguous
    ushort* kb = qb + nx;
    ushort* vb = kb + nx;
    ushort* yb = vb + nx;

    dim3 blk(256);
    hipLaunchKernelGGL(cast_x, dim3((nx / 4 + 255) / 256), blk, 0, stream, x, xb, (int)nx);
    hipLaunchKernelGGL(cast_w4, dim3((nw / 4 + 255) / 256, 4), blk, 0, stream,
                       Wq, Wk, Wv, Wo, wb, (int)nw);

    const int M = B_ * S_;
    dim3 gqkv(3072 / 128, M / 128);           // 1536 blocks, %8==0
    hipLaunchKernelGGL((gemm128<0>), gqkv, blk, 0, stream, xb, wb, qb, M, 3072, D_);

    dim3 gattn(2048);                         // QBLK=64; kernel does XCD grouping
    hipLaunchKernelGGL(attn_mfma, gattn, blk, 0, stream, qb, kb, vb, yb);

    dim3 gproj(D_ / 128, M / 128);            // 512 blocks
    hipLaunchKernelGGL((gemm128<1>), gproj, blk, 0, stream, yb, wb + 3 * nw, out, M, D_, D_);
}